// Round 1
// baseline (155.675 us; speedup 1.0000x reference)
//
#include <hip/hip_runtime.h>
#include <math.h>

#define CCH 512      // channels
#define FH 76        // feature H
#define FW 128       // feature W
#define NP 256       // proposals
#define HID 200      // hidden width

// ---------------- Kernel 1: ROI adaptive 2x2 max-pool ----------------
// grid (256 proposals, 4 bins), block 512 (one thread per channel).
// Also zeroes h1_raw (needed because ws is poisoned 0xAA before every launch).
__global__ __launch_bounds__(512) void pool_kernel(
    const float* __restrict__ fm, const int* __restrict__ coords,
    float* __restrict__ f, float* __restrict__ h1_raw)
{
    const int n   = blockIdx.x;
    const int bin = blockIdx.y;          // (by,bx) = (bin>>1, bin&1)
    const int by = bin >> 1, bx = bin & 1;
    const int c0 = coords[n*4+0], c1 = coords[n*4+1];
    const int c2 = coords[n*4+2], c3 = coords[n*4+3];
    const int sy = min(c0 >> 3, FH - 2);
    const int sx = min(c1 >> 3, FW - 2);
    const int ey = (c2 + 7) >> 3;
    const int ex = (c3 + 7) >> 3;
    const int h = max(ey - sy, 2);
    const int w = max(ex - sx, 2);
    // adaptive bin i covers [i*size/2, ((i+1)*size+1)/2)
    const int rs = by ? (h >> 1) : 0;
    const int re = by ? h : ((h + 1) >> 1);
    const int cs = bx ? (w >> 1) : 0;
    const int ce = bx ? w : ((w + 1) >> 1);
    const int c = threadIdx.x;
    float m = -1e30f;
    for (int r = rs; r < re; ++r) {
        const float* row = fm + (((size_t)(sy + r) * FW) + sx + cs) * CCH + c;
        for (int cc = 0; cc < ce - cs; ++cc)
            m = fmaxf(m, row[(size_t)cc * CCH]);
    }
    f[(size_t)n * (4*CCH) + bin * CCH + c] = m;
    if (bin == 0 && c < HID) h1_raw[n * HID + c] = 0.0f;
}

// ---------------- Kernel 2: layer1 split-K GEMM ----------------
// h1_raw[n][j] += sum_k f[n][k] * W1[k][j]   (bias+relu applied by consumer)
// grid (16 row-tiles, 16 k-chunks), block 256 (thread j = output column).
#define L1_ROWS 16
#define L1_KC   128
__global__ __launch_bounds__(256) void l1_kernel(
    const float* __restrict__ f, const float* __restrict__ W1,
    float* __restrict__ h1_raw)
{
    const int j = threadIdx.x;
    if (j >= HID) return;
    const int r0 = blockIdx.x * L1_ROWS;
    const int k0 = blockIdx.y * L1_KC;
    float acc[L1_ROWS];
    #pragma unroll
    for (int r = 0; r < L1_ROWS; ++r) acc[r] = 0.0f;
    const float* fp = f  + (size_t)r0 * 2048 + k0;   // wave-uniform -> s_load path
    const float* wp = W1 + (size_t)k0 * HID + j;     // coalesced across j
    for (int k = 0; k < L1_KC; ++k) {
        const float wv = wp[(size_t)k * HID];
        #pragma unroll
        for (int r = 0; r < L1_ROWS; ++r)
            acc[r] += fp[(size_t)r * 2048 + k] * wv;
    }
    #pragma unroll
    for (int r = 0; r < L1_ROWS; ++r)
        atomicAdd(&h1_raw[(r0 + r) * HID + j], acc[r]);
}

// ---------------- Kernel 3: layer2 + heads + postprocess ----------------
// One block per proposal (rows are fully independent after GEMM1).
__global__ __launch_bounds__(256) void head_kernel(
    const float* __restrict__ h1_raw,
    const float* __restrict__ b1, const float* __restrict__ W2,
    const float* __restrict__ b2, const float* __restrict__ W3,
    const float* __restrict__ b3, const float* __restrict__ W4,
    const float* __restrict__ b4, const int* __restrict__ coords,
    float* __restrict__ out)
{
    __shared__ float h1s[HID];
    __shared__ float h2s[HID];
    __shared__ float hd[21];     // 16 reg + 5 cls
    const int n = blockIdx.x;
    const int t = threadIdx.x;
    if (t < HID) h1s[t] = fmaxf(h1_raw[n * HID + t] + b1[t], 0.0f);
    __syncthreads();
    if (t < HID) {
        float acc = b2[t];
        for (int k = 0; k < HID; ++k)
            acc += h1s[k] * W2[k * HID + t];
        h2s[t] = fmaxf(acc, 0.0f);
    }
    __syncthreads();
    if (t < 21) {
        float acc;
        if (t < 16) {
            acc = b3[t];
            for (int k = 0; k < HID; ++k) acc += h2s[k] * W3[k * 16 + t];
        } else {
            const int ci = t - 16;
            acc = b4[ci];
            for (int k = 0; k < HID; ++k) acc += h2s[k] * W4[k * 5 + ci];
        }
        hd[t] = acc;
    }
    __syncthreads();
    if (t == 0) {
        const float cv0 = hd[16], cv1 = hd[17], cv2 = hd[18],
                    cv3 = hd[19], cv4 = hd[20];
        // jnp.argmax: first occurrence of max -> strict '>'
        int cls = 0; float best = cv0;
        if (cv1 > best) { best = cv1; cls = 1; }
        if (cv2 > best) { best = cv2; cls = 2; }
        if (cv3 > best) { best = cv3; cls = 3; }
        if (cv4 > best) { best = cv4; cls = 4; }
        const float e0 = expf(cv0 - best), e1 = expf(cv1 - best),
                    e2 = expf(cv2 - best), e3 = expf(cv3 - best),
                    e4 = expf(cv4 - best);
        const float s = e0 + e1 + e2 + e3 + e4;
        const float score = fmaxf(fmaxf(e1, e2), fmaxf(e3, e4)) / s;
        const int ri = max(cls - 1, 0);
        const float rg0 = hd[ri*4+0], rg1 = hd[ri*4+1],
                    rg2 = hd[ri*4+2], rg3 = hd[ri*4+3];
        const float y0 = (float)coords[n*4+0], x0 = (float)coords[n*4+1];
        const float y1 = (float)coords[n*4+2], x1 = (float)coords[n*4+3];
        const float ph = y1 - y0, pw = x1 - x0;
        const float py = y0 + 0.5f * ph, px = x0 + 0.5f * pw;
        const float oy = ph * rg0 + py;
        const float ox = pw * rg1 + px;
        const float oh = ph * fminf(fmaxf(expf(rg2), 0.001f), 20.0f);
        const float ow = pw * fminf(fmaxf(expf(rg3), 0.001f), 20.0f);
        out[n*4+0] = oy; out[n*4+1] = ox; out[n*4+2] = oh; out[n*4+3] = ow;
        out[NP*4 + n] = score;                       // scores block
        out[NP*5 + n] = (cls != 0) ? 1.0f : 0.0f;    // mask block (bool as fp32)
    }
}

extern "C" void kernel_launch(void* const* d_in, const int* in_sizes, int n_in,
                              void* d_out, int out_size, void* d_ws, size_t ws_size,
                              hipStream_t stream) {
    const float* fm     = (const float*)d_in[0];   // [1,76,128,512]
    const int*   coords = (const int*)  d_in[1];   // [256,4]
    const float* W1 = (const float*)d_in[2];       // [2048,200]
    const float* b1 = (const float*)d_in[3];
    const float* W2 = (const float*)d_in[4];       // [200,200]
    const float* b2 = (const float*)d_in[5];
    const float* W3 = (const float*)d_in[6];       // [200,16]
    const float* b3 = (const float*)d_in[7];
    const float* W4 = (const float*)d_in[8];       // [200,5]
    const float* b4 = (const float*)d_in[9];
    float* out = (float*)d_out;                    // 1024 boxes + 256 scores + 256 mask

    float* f      = (float*)d_ws;                  // [256, 2048]
    float* h1_raw = f + (size_t)NP * 2048;         // [256, 200]

    pool_kernel<<<dim3(NP, 4), 512, 0, stream>>>(fm, coords, f, h1_raw);
    l1_kernel  <<<dim3(16, 16), 256, 0, stream>>>(f, W1, h1_raw);
    head_kernel<<<NP, 256, 0, stream>>>(h1_raw, b1, W2, b2, W3, b3, W4, b4,
                                        coords, out);
}